// Round 9
// baseline (124.432 us; speedup 1.0000x reference)
//
#include <hip/hip_runtime.h>
#include <math.h>

#define B_    8
#define T_    2000
#define H_    256
#define FOUT_ 257
#define ALEN_ 128

typedef __attribute__((ext_vector_type(8))) short bf16x8;
typedef __attribute__((ext_vector_type(4))) float f32x4;
typedef __attribute__((ext_vector_type(16))) float f32x16;
typedef __attribute__((ext_vector_type(8))) unsigned short u16x8;

// ---------------------------------------------------------------------------
// truncation split: x = hi + lo exactly at f32
__device__ __forceinline__ void split1(float x, unsigned short& h, unsigned short& l) {
    unsigned u = __builtin_bit_cast(unsigned, x);
    h = (unsigned short)(u >> 16);
    float hf = __builtin_bit_cast(float, u & 0xFFFF0000u);
    l = (unsigned short)(__builtin_bit_cast(unsigned, x - hf) >> 16);
}
__device__ __forceinline__ void split8(float4 f0, float4 f1, bf16x8& h, bf16x8& l) {
    float f[8] = {f0.x, f0.y, f0.z, f0.w, f1.x, f1.y, f1.z, f1.w};
#pragma unroll
    for (int i = 0; i < 8; ++i) {
        unsigned short hh, ll;
        split1(f[i], hh, ll);
        h[i] = (short)hh; l[i] = (short)ll;
    }
}
__device__ __forceinline__ void gld16(const void* g, void* l) {
    __builtin_amdgcn_global_load_lds(
        (const __attribute__((address_space(1))) unsigned*)g,
        (__attribute__((address_space(3))) unsigned*)l, 16, 0, 0);
}

// ---------------------------------------------------------------------------
// prep: one kernel for all preprocessing.
//  blocks [0,2000):    qsplit  q -> q2h/q2l
//  blocks [2000,3008): k: (a) row-major hi/lo split -> kh/kl (QK^T B-operand,
//                      hoists the 9x-redundant in-kernel split8 out of attn);
//                      (b) PV-frag-ordered bf16-hi K^T -> ktn
//                      ktn[b][ht(16)][g(126)][half(2)][lq(16)][e(8)],
//                      element (b, h=ht*16+lq, s=g*16+half*8+e); g=125 zero.
//  blocks [3008,3264): W_score split
//  blocks [3264,3776): W_enh split
//  blocks [3776,4288): W_mask split, padded to 512x256 (zero rows >= 257)
__global__ __launch_bounds__(256) void prep(
    const float* __restrict__ k, const float* __restrict__ q,
    const float* __restrict__ Ws, const float* __restrict__ We,
    const float* __restrict__ Wm,
    unsigned short* __restrict__ q2h, unsigned short* __restrict__ q2l,
    unsigned short* __restrict__ kh, unsigned short* __restrict__ kl,
    unsigned short* __restrict__ ktn,
    unsigned short* __restrict__ wsh, unsigned short* __restrict__ wsl,
    unsigned short* __restrict__ weh, unsigned short* __restrict__ wel,
    unsigned short* __restrict__ wmh, unsigned short* __restrict__ wml)
{
    __shared__ float tile[16][260];
    const int bx = blockIdx.x, tid = threadIdx.x;

    if (bx < 2000) {                     // ---- qsplit (8 elems/thread)
        const size_t i = ((size_t)bx * 256 + tid) * 8;
        const float4 f0 = *(const float4*)(q + i);
        const float4 f1 = *(const float4*)(q + i + 4);
        bf16x8 h, l;
        split8(f0, f1, h, l);
        *(bf16x8*)(q2h + i) = h;
        *(bf16x8*)(q2l + i) = l;
    } else if (bx < 3008) {              // ---- k prep
        const int bid = bx - 2000;
        const int b = bid / 126;
        const int g = bid % 126;
        const int s0 = g * 16;
        const int r = tid >> 4, cs = (tid & 15) * 16;
        const int s = s0 + r;
        if (s < T_) {
            const size_t ko = ((size_t)b * T_ + s) * H_ + cs;
            const float* src = k + ko;
#pragma unroll
            for (int i = 0; i < 2; ++i) {
                const float4 v0 = *(const float4*)(src + i * 8);
                const float4 v1 = *(const float4*)(src + i * 8 + 4);
                bf16x8 h, l;
                split8(v0, v1, h, l);
                *(bf16x8*)(kh + ko + i * 8) = h;
                *(bf16x8*)(kl + ko + i * 8) = l;
                const float ff[8] = {v0.x, v0.y, v0.z, v0.w, v1.x, v1.y, v1.z, v1.w};
#pragma unroll
                for (int j = 0; j < 8; ++j) tile[r][cs + i * 8 + j] = ff[j];
            }
        } else {
#pragma unroll
            for (int i = 0; i < 16; ++i) tile[r][cs + i] = 0.f;
        }
        __syncthreads();
        const int h = tid;               // column of the 16x256 tile
        const int ht = h >> 4, lq = h & 15;
        u16x8 o0, o1;
#pragma unroll
        for (int ss = 0; ss < 8; ++ss)
            o0[ss] = (unsigned short)(__builtin_bit_cast(unsigned, tile[ss][h]) >> 16);
#pragma unroll
        for (int ss = 0; ss < 8; ++ss)
            o1[ss] = (unsigned short)(__builtin_bit_cast(unsigned, tile[ss + 8][h]) >> 16);
        unsigned short* dst = ktn + (((size_t)(b * 16 + ht) * 126) + g) * 256 + lq * 8;
        *(u16x8*)(dst) = o0;             // half 0: s = g*16 + 0..7
        *(u16x8*)(dst + 128) = o1;       // half 1: s = g*16 + 8..15
    } else if (bx < 3264) {              // ---- W_score
        const int idx = (bx - 3008) * 256 + tid;
        unsigned short h, l; split1(Ws[idx], h, l);
        wsh[idx] = h; wsl[idx] = l;
    } else if (bx < 3776) {              // ---- W_enh
        const int idx = (bx - 3264) * 256 + tid;
        unsigned short h, l; split1(We[idx], h, l);
        weh[idx] = h; wel[idx] = l;
    } else {                             // ---- W_mask (padded to 512 rows)
        const int idx = (bx - 3776) * 256 + tid;
        const int r2 = idx >> 8;
        const float x = (r2 < FOUT_) ? Wm[idx] : 0.f;
        unsigned short h, l; split1(x, h, l);
        wmh[idx] = h; wml[idx] = l;
    }
}

// ---------------------------------------------------------------------------
// Split-bf16 MFMA GEMM v3 (R7-proven): BM=64, BN=256, A staged exactly once.
template <int ACT, bool HAS_A2, bool SPLITOUT>
__global__ __launch_bounds__(256) void gemm_mfma(
    const unsigned short* __restrict__ Ah1, const unsigned short* __restrict__ Al1,
    const unsigned short* __restrict__ Ah2, const unsigned short* __restrict__ Al2,
    const unsigned short* __restrict__ Wh, const unsigned short* __restrict__ Wl,
    const float* __restrict__ bias, float* __restrict__ C,
    unsigned short* __restrict__ Ch, unsigned short* __restrict__ Cl,
    int NT, int KB, int NSTORE, int LDC)
{
    __shared__ char AS[2][64 * 128];     // 2 x 8 KB
    __shared__ char WS[2][256 * 128];    // 2 x 32 KB

    const int tid = threadIdx.x;
    const int m0 = blockIdx.x * 64;
    const int n0 = blockIdx.y * 256;
    const int w = tid >> 6, l = tid & 63;
    const int lm = l & 31, hh = l >> 5;

    f32x16 acc00 = {}, acc01 = {}, acc10 = {}, acc11 = {};

    auto STAGEA = [&](int kt, int buf) {
        const int k0g = kt * 32;
        const unsigned short* Hs = Ah1;
        const unsigned short* Ls = Al1;
        int k0 = k0g;
        if (HAS_A2 && k0g >= 256) { Hs = Ah2; Ls = Al2; k0 = k0g - 256; }
#pragma unroll
        for (int p = 0; p < 2; ++p) {
            const unsigned D = p * 4096u + tid * 16u;
            const unsigned row = D >> 7;
            const unsigned u = (D & 127u) ^ ((row & 7u) << 4);
            const unsigned kelem = (u & 63u) >> 1;
            const unsigned short* src =
                ((u >> 6) ? Ls : Hs) + (size_t)(m0 + row) * 256 + k0 + kelem;
            gld16(src, AS[buf] + (p * 4 + w) * 1024);
        }
    };
    auto STAGEW = [&](int kt, int buf) {
        const int k0g = kt * 32;
#pragma unroll
        for (int p = 0; p < 8; ++p) {
            const unsigned D = p * 4096u + tid * 16u;
            const unsigned row = D >> 7;
            const unsigned u = (D & 127u) ^ ((row & 7u) << 4);
            const unsigned kelem = (u & 63u) >> 1;
            const unsigned short* src =
                ((u >> 6) ? Wl : Wh) + (size_t)(n0 + row) * KB + k0g + kelem;
            gld16(src, WS[buf] + (p * 4 + w) * 1024);
        }
    };

    STAGEA(0, 0);
    STAGEW(0, 0);
    __syncthreads();

    int buf = 0;
    for (int kt = 0; kt < NT; ++kt) {
        const bool last = (kt == NT - 1);
        if (!last) { STAGEA(kt + 1, buf ^ 1); STAGEW(kt + 1, buf ^ 1); }

        const unsigned r_a = (unsigned)lm;
        const unsigned swa = (r_a & 7u) << 4;
        const unsigned r_b = (unsigned)(w * 64 + lm);
        const unsigned swb = (r_b & 7u) << 4;
#pragma unroll
        for (int kc = 0; kc < 2; ++kc) {
            const unsigned u = (unsigned)(kc * 32 + hh * 16);
            const bf16x8 ah0 = *(const bf16x8*)(AS[buf] + r_a * 128 + (u ^ swa));
            const bf16x8 al0 = *(const bf16x8*)(AS[buf] + r_a * 128 + ((u + 64) ^ swa));
            const bf16x8 ah1 = *(const bf16x8*)(AS[buf] + (r_a + 32) * 128 + (u ^ swa));
            const bf16x8 al1 = *(const bf16x8*)(AS[buf] + (r_a + 32) * 128 + ((u + 64) ^ swa));
            const bf16x8 bh0 = *(const bf16x8*)(WS[buf] + r_b * 128 + (u ^ swb));
            const bf16x8 bl0 = *(const bf16x8*)(WS[buf] + r_b * 128 + ((u + 64) ^ swb));
            const bf16x8 bh1 = *(const bf16x8*)(WS[buf] + (r_b + 32) * 128 + (u ^ swb));
            const bf16x8 bl1 = *(const bf16x8*)(WS[buf] + (r_b + 32) * 128 + ((u + 64) ^ swb));
            acc00 = __builtin_amdgcn_mfma_f32_32x32x16_bf16(ah0, bh0, acc00, 0, 0, 0);
            acc00 = __builtin_amdgcn_mfma_f32_32x32x16_bf16(ah0, bl0, acc00, 0, 0, 0);
            acc00 = __builtin_amdgcn_mfma_f32_32x32x16_bf16(al0, bh0, acc00, 0, 0, 0);
            acc01 = __builtin_amdgcn_mfma_f32_32x32x16_bf16(ah0, bh1, acc01, 0, 0, 0);
            acc01 = __builtin_amdgcn_mfma_f32_32x32x16_bf16(ah0, bl1, acc01, 0, 0, 0);
            acc01 = __builtin_amdgcn_mfma_f32_32x32x16_bf16(al0, bh1, acc01, 0, 0, 0);
            acc10 = __builtin_amdgcn_mfma_f32_32x32x16_bf16(ah1, bh0, acc10, 0, 0, 0);
            acc10 = __builtin_amdgcn_mfma_f32_32x32x16_bf16(ah1, bl0, acc10, 0, 0, 0);
            acc10 = __builtin_amdgcn_mfma_f32_32x32x16_bf16(al1, bh0, acc10, 0, 0, 0);
            acc11 = __builtin_amdgcn_mfma_f32_32x32x16_bf16(ah1, bh1, acc11, 0, 0, 0);
            acc11 = __builtin_amdgcn_mfma_f32_32x32x16_bf16(ah1, bl1, acc11, 0, 0, 0);
            acc11 = __builtin_amdgcn_mfma_f32_32x32x16_bf16(al1, bh1, acc11, 0, 0, 0);
        }
        __syncthreads();
        buf ^= 1;
    }

    // epilogue: C/D layout col=lane&31, row=(reg&3)+8*(reg>>2)+4*(lane>>5)
#pragma unroll
    for (int rt = 0; rt < 2; ++rt) {
#pragma unroll
        for (int ct = 0; ct < 2; ++ct) {
            const f32x16 r = rt ? (ct ? acc11 : acc10) : (ct ? acc01 : acc00);
            const int gcol = n0 + w * 64 + ct * 32 + lm;
            if (gcol < NSTORE) {
                const float bv = bias ? bias[gcol] : 0.f;
#pragma unroll
                for (int e = 0; e < 16; ++e) {
                    const int rowl = (e & 3) + 8 * (e >> 2) + 4 * hh;
                    const int gr = m0 + rt * 32 + rowl;
                    float x = r[e] + bv;
                    if constexpr (ACT == 1) x = tanhf(x);
                    else if constexpr (ACT == 2) x = 1.f / (1.f + expf(-x));
                    if constexpr (SPLITOUT) {
                        unsigned short hh2, ll2;
                        split1(x, hh2, ll2);
                        Ch[(size_t)gr * LDC + gcol] = hh2;
                        Cl[(size_t)gr * LDC + gcol] = ll2;
                    } else {
                        C[(size_t)gr * LDC + gcol] = x;
                    }
                }
            }
        }
    }
}

// ---------------------------------------------------------------------------
// MFMA banded attention v5: QK^T B-operand from pre-split kh/kl (bf16x8
// direct loads, no in-kernel split VALU); XCD-local b = bid&7; PV from
// frag-ordered ktn. Arithmetic bit-identical to v4.
__global__ __launch_bounds__(256) void band_attn_mfma(
    const unsigned short* __restrict__ qh, const unsigned short* __restrict__ ql,
    const unsigned short* __restrict__ kh, const unsigned short* __restrict__ kl,
    const unsigned short* __restrict__ ktn,
    unsigned short* __restrict__ Ch, unsigned short* __restrict__ Cl)
{
    __shared__ float S[16][164];
    __shared__ unsigned short PH[16][168];
    __shared__ unsigned short PL[16][168];

    const int bid = blockIdx.x;
    const int b = bid & 7;
    const int t0 = (bid >> 3) * 16;
    const int tid = threadIdx.x;
    const int w = tid >> 6, l = tid & 63;
    const int lq = l & 15;
    const int lk = l >> 4;
    const int s_lo = max(0, t0 - ALEN_);
    const size_t qrow = (size_t)b * T_ + t0;
    const size_t kb = (size_t)b * T_ * H_;

    // ---- QK^T ----
    bf16x8 aH[8], aL[8];
#pragma unroll
    for (int hc = 0; hc < 8; ++hc) {
        const size_t o = (qrow + lq) * H_ + hc * 32 + lk * 8;
        aH[hc] = *(const bf16x8*)(qh + o);
        aL[hc] = *(const bf16x8*)(ql + o);
    }
    for (int st = w; st < 9; st += 4) {
        f32x4 acc = {};
        const int s = s_lo + st * 16 + lq;
        const size_t ro = kb + (size_t)s * H_ + lk * 8;
#pragma unroll
        for (int hc = 0; hc < 8; ++hc) {
            const bf16x8 bh = *(const bf16x8*)(kh + ro + hc * 32);
            const bf16x8 bl = *(const bf16x8*)(kl + ro + hc * 32);
            acc = __builtin_amdgcn_mfma_f32_16x16x32_bf16(aH[hc], bh, acc, 0, 0, 0);
            acc = __builtin_amdgcn_mfma_f32_16x16x32_bf16(aH[hc], bl, acc, 0, 0, 0);
            acc = __builtin_amdgcn_mfma_f32_16x16x32_bf16(aL[hc], bh, acc, 0, 0, 0);
        }
#pragma unroll
        for (int r = 0; r < 4; ++r)
            S[lk * 4 + r][st * 16 + lq] = acc[r];
    }
    __syncthreads();

    // ---- softmax (band-masked, P pre-scaled by 1/denom) ----
    {
        const int q = tid >> 4, li = tid & 15;
        const int t = t0 + q;
        const int jlo = max(0, t - ALEN_) - s_lo;
        const int jhi = t - s_lo;
        float m = -INFINITY;
#pragma unroll
        for (int j = 0; j < 10; ++j) {
            const int s = li + j * 16;
            if (s >= jlo && s <= jhi) m = fmaxf(m, S[q][s]);
        }
#pragma unroll
        for (int off = 8; off; off >>= 1) m = fmaxf(m, __shfl_xor(m, off));
        float sum = 0.f;
#pragma unroll
        for (int j = 0; j < 10; ++j) {
            const int s = li + j * 16;
            const float e = (s >= jlo && s <= jhi) ? expf(S[q][s] - m) : 0.f;
            S[q][s] = e;
            sum += e;
        }
#pragma unroll
        for (int off = 8; off; off >>= 1) sum += __shfl_xor(sum, off);
        const float inv = 1.f / (sum + 1e-30f);
#pragma unroll
        for (int j = 0; j < 10; ++j) {
            const int s = li + j * 16;
            unsigned short hh2, ll2;
            split1(S[q][s] * inv, hh2, ll2);
            PH[q][s] = hh2;
            PL[q][s] = ll2;
        }
    }
    __syncthreads();

    // ---- PV (frag-ordered ktn reads) ----
    const int gbase = s_lo >> 4;
    for (int ht = w; ht < 16; ht += 4) {
        f32x4 acc = {};
        const unsigned short* ktb = ktn + ((size_t)(b * 16 + ht) * 126) * 256;
#pragma unroll
        for (int sc = 0; sc < 5; ++sc) {
            const bf16x8 ph = *(const bf16x8*)((const char*)&PH[lq][0] + sc * 64 + lk * 16);
            const bf16x8 pl = *(const bf16x8*)((const char*)&PL[lq][0] + sc * 64 + lk * 16);
            const bf16x8 bt = *(const bf16x8*)(
                ktb + (size_t)(gbase + 2 * sc + (lk >> 1)) * 256 + (lk & 1) * 128 + lq * 8);
            acc = __builtin_amdgcn_mfma_f32_16x16x32_bf16(ph, bt, acc, 0, 0, 0);
            acc = __builtin_amdgcn_mfma_f32_16x16x32_bf16(pl, bt, acc, 0, 0, 0);
        }
#pragma unroll
        for (int r = 0; r < 4; ++r) {
            unsigned short hh2, ll2;
            split1(acc[r], hh2, ll2);
            const size_t o = (qrow + lk * 4 + r) * H_ + ht * 16 + lq;
            Ch[o] = hh2;
            Cl[o] = ll2;
        }
    }
}

// ---------------------------------------------------------------------------
extern "C" void kernel_launch(void* const* d_in, const int* in_sizes, int n_in,
                              void* d_out, int out_size, void* d_ws, size_t ws_size,
                              hipStream_t stream)
{
    const float* k       = (const float*)d_in[0];
    const float* q       = (const float*)d_in[1];
    const float* W_score = (const float*)d_in[2];
    const float* W_enh   = (const float*)d_in[3];
    const float* b_enh   = (const float*)d_in[4];
    const float* W_mask  = (const float*)d_in[5];
    const float* b_mask  = (const float*)d_in[6];
    float* out = (float*)d_out;

    const size_t MH = (size_t)B_ * T_ * H_;          // 4.096M elems
    unsigned short* q2h = (unsigned short*)d_ws;     // 8.19 MB each
    unsigned short* q2l = q2h + MH;
    unsigned short* qh  = q2l + MH;
    unsigned short* ql  = qh + MH;
    unsigned short* ch  = ql + MH;
    unsigned short* cl  = ch + MH;
    unsigned short* kh  = cl + MH;
    unsigned short* kl  = kh + MH;
    unsigned short* ktn = kl + MH;                   // 8*16*126*256 = 4,128,768
    unsigned short* wsh = ktn + (size_t)B_ * 16 * 126 * 256;
    unsigned short* wsl = wsh + 65536;
    unsigned short* weh = wsl + 65536;
    unsigned short* wel = weh + 131072;
    unsigned short* wmh = wel + 131072;              // 512x256 padded
    unsigned short* wml = wmh + 131072;
    unsigned short* eh = qh;                         // alias: qs dead after attn
    unsigned short* el = ql;

    dim3 blk(256);

    prep<<<dim3(4288), blk, 0, stream>>>(
        k, q, W_score, W_enh, W_mask,
        q2h, q2l, kh, kl, ktn, wsh, wsl, weh, wel, wmh, wml);

    // qs (split bf16) = q @ W_score^T
    gemm_mfma<0, false, true><<<dim3(250, 1), blk, 0, stream>>>(
        q2h, q2l, nullptr, nullptr, wsh, wsl, nullptr, nullptr, qh, ql,
        8, 256, 256, 256);

    band_attn_mfma<<<dim3(1000), blk, 0, stream>>>(qh, ql, kh, kl, ktn, ch, cl);

    // enh (split bf16) = tanh([c,q] @ W_enh^T + b_enh)
    gemm_mfma<1, true, true><<<dim3(250, 1), blk, 0, stream>>>(
        ch, cl, q2h, q2l, weh, wel, b_enh, nullptr, eh, el,
        16, 512, 256, 256);

    // out = sigmoid(enh @ W_mask^T + b_mask)
    gemm_mfma<2, false, false><<<dim3(250, 2), blk, 0, stream>>>(
        eh, el, nullptr, nullptr, wmh, wml, b_mask, out, nullptr, nullptr,
        8, 256, 257, 257);
}

// Round 11
// 109.426 us; speedup vs baseline: 1.1371x; 1.1371x over previous
//
#include <hip/hip_runtime.h>
#include <math.h>

#define B_    8
#define T_    2000
#define H_    256
#define FOUT_ 257
#define ALEN_ 128

typedef __attribute__((ext_vector_type(8))) short bf16x8;
typedef __attribute__((ext_vector_type(4))) float f32x4;
typedef __attribute__((ext_vector_type(16))) float f32x16;
typedef __attribute__((ext_vector_type(8))) unsigned short u16x8;

// ---------------------------------------------------------------------------
// truncation split: x = hi + lo exactly at f32
__device__ __forceinline__ void split1(float x, unsigned short& h, unsigned short& l) {
    unsigned u = __builtin_bit_cast(unsigned, x);
    h = (unsigned short)(u >> 16);
    float hf = __builtin_bit_cast(float, u & 0xFFFF0000u);
    l = (unsigned short)(__builtin_bit_cast(unsigned, x - hf) >> 16);
}
__device__ __forceinline__ void split8(float4 f0, float4 f1, bf16x8& h, bf16x8& l) {
    float f[8] = {f0.x, f0.y, f0.z, f0.w, f1.x, f1.y, f1.z, f1.w};
#pragma unroll
    for (int i = 0; i < 8; ++i) {
        unsigned short hh, ll;
        split1(f[i], hh, ll);
        h[i] = (short)hh; l[i] = (short)ll;
    }
}
__device__ __forceinline__ void gld16(const void* g, void* l) {
    __builtin_amdgcn_global_load_lds(
        (const __attribute__((address_space(1))) unsigned*)g,
        (__attribute__((address_space(3))) unsigned*)l, 16, 0, 0);
}

// ---------------------------------------------------------------------------
// prep:
//  [0,2000):    qsplit  q -> q2h/q2l
//  [2000,3008): k -> kh/kl (row-major split) + ktn (PV-frag-ordered bf16-hi)
//  [3008,3264): W_score -> wsn (frag-ordered for attn qs-phase B):
//               wsn[ht(16)][kg(8)][lk(4)][lq(16)][e(8)],
//               elem = Ws[ht*16+lq][kg*32+lk*8+e]
//  [3264,3776): W_enh split (row-major, gemm staging)
//  [3776,4288): W_mask -> wmn (frag-ordered for fused out-GEMM B):
//               wmn[nt(10)][f(16)][hh(2)][lm(32)][e(8)],
//               elem = Wm[nt*32+lm][f*16+hh*8+e]; rows 257..319 zero.
__global__ __launch_bounds__(256) void prep(
    const float* __restrict__ k, const float* __restrict__ q,
    const float* __restrict__ Ws, const float* __restrict__ We,
    const float* __restrict__ Wm,
    unsigned short* __restrict__ q2h, unsigned short* __restrict__ q2l,
    unsigned short* __restrict__ kh, unsigned short* __restrict__ kl,
    unsigned short* __restrict__ ktn,
    unsigned short* __restrict__ wsnh, unsigned short* __restrict__ wsnl,
    unsigned short* __restrict__ weh, unsigned short* __restrict__ wel,
    unsigned short* __restrict__ wmnh, unsigned short* __restrict__ wmnl)
{
    __shared__ float tile[16][260];
    const int bx = blockIdx.x, tid = threadIdx.x;

    if (bx < 2000) {                     // ---- qsplit
        const size_t i = ((size_t)bx * 256 + tid) * 8;
        const float4 f0 = *(const float4*)(q + i);
        const float4 f1 = *(const float4*)(q + i + 4);
        bf16x8 h, l;
        split8(f0, f1, h, l);
        *(bf16x8*)(q2h + i) = h;
        *(bf16x8*)(q2l + i) = l;
    } else if (bx < 3008) {              // ---- k prep
        const int bid = bx - 2000;
        const int b = bid / 126;
        const int g = bid % 126;
        const int s0 = g * 16;
        const int r = tid >> 4, cs = (tid & 15) * 16;
        const int s = s0 + r;
        if (s < T_) {
            const size_t ko = ((size_t)b * T_ + s) * H_ + cs;
            const float* src = k + ko;
#pragma unroll
            for (int i = 0; i < 2; ++i) {
                const float4 v0 = *(const float4*)(src + i * 8);
                const float4 v1 = *(const float4*)(src + i * 8 + 4);
                bf16x8 h, l;
                split8(v0, v1, h, l);
                *(bf16x8*)(kh + ko + i * 8) = h;
                *(bf16x8*)(kl + ko + i * 8) = l;
                const float ff[8] = {v0.x, v0.y, v0.z, v0.w, v1.x, v1.y, v1.z, v1.w};
#pragma unroll
                for (int j = 0; j < 8; ++j) tile[r][cs + i * 8 + j] = ff[j];
            }
        } else {
#pragma unroll
            for (int i = 0; i < 16; ++i) tile[r][cs + i] = 0.f;
        }
        __syncthreads();
        const int h = tid;
        const int ht = h >> 4, lq = h & 15;
        u16x8 o0, o1;
#pragma unroll
        for (int ss = 0; ss < 8; ++ss)
            o0[ss] = (unsigned short)(__builtin_bit_cast(unsigned, tile[ss][h]) >> 16);
#pragma unroll
        for (int ss = 0; ss < 8; ++ss)
            o1[ss] = (unsigned short)(__builtin_bit_cast(unsigned, tile[ss + 8][h]) >> 16);
        unsigned short* dst = ktn + (((size_t)(b * 16 + ht) * 126) + g) * 256 + lq * 8;
        *(u16x8*)(dst) = o0;
        *(u16x8*)(dst + 128) = o1;
    } else if (bx < 3264) {              // ---- W_score -> wsn
        const int g = bx - 3008;         // row 0..255
        const int hcol = tid;            // col 0..255
        unsigned short h, l; split1(Ws[g * 256 + hcol], h, l);
        const int ht = g >> 4, lq = g & 15;
        const int kg = hcol >> 5, lk = (hcol >> 3) & 3, e = hcol & 7;
        const int off = ((ht * 8 + kg) * 64 + lk * 16 + lq) * 8 + e;
        wsnh[off] = h; wsnl[off] = l;
    } else if (bx < 3776) {              // ---- W_enh
        const int idx = (bx - 3264) * 256 + tid;
        unsigned short h, l; split1(We[idx], h, l);
        weh[idx] = h; wel[idx] = l;
    } else {                             // ---- W_mask -> wmn (rows < 320)
        const int r2 = bx - 3776;        // row (out col) 0..511
        if (r2 < 320) {
            const float x = (r2 < FOUT_) ? Wm[r2 * 256 + tid] : 0.f;
            unsigned short h, l; split1(x, h, l);
            const int nt = r2 >> 5, lm = r2 & 31;
            const int f = tid >> 4, hh = (tid >> 3) & 1, e = tid & 7;
            const int off = (((nt * 16 + f) * 2 + hh) * 32 + lm) * 8 + e;
            wmnh[off] = h; wmnl[off] = l;
        }
    }
}

// ---------------------------------------------------------------------------
// Fused banded attention: phase0 computes qs = q @ Ws^T in-block (replaces
// gemm1; zero redundant FLOPs since each q-row belongs to exactly one block),
// then QK^T (kh/kl), band softmax, PV (frag-ordered ktn). XCD-local b=bid&7.
__global__ __launch_bounds__(256) void band_attn_mfma(
    const unsigned short* __restrict__ q2h, const unsigned short* __restrict__ q2l,
    const unsigned short* __restrict__ wsnh, const unsigned short* __restrict__ wsnl,
    const unsigned short* __restrict__ kh, const unsigned short* __restrict__ kl,
    const unsigned short* __restrict__ ktn,
    unsigned short* __restrict__ Ch, unsigned short* __restrict__ Cl)
{
    __shared__ float S[16][164];
    __shared__ unsigned short PH[16][168];
    __shared__ unsigned short PL[16][168];
    __shared__ unsigned short QSH[16 * 256];
    __shared__ unsigned short QSL[16 * 256];

    const int bid = blockIdx.x;
    const int b = bid & 7;
    const int t0 = (bid >> 3) * 16;
    const int tid = threadIdx.x;
    const int w = tid >> 6, l = tid & 63;
    const int lq = l & 15;
    const int lk = l >> 4;
    const int s_lo = max(0, t0 - ALEN_);
    const size_t qrow = (size_t)b * T_ + t0;
    const size_t kb = (size_t)b * T_ * H_;

    // ---- phase 0: qs tile = q2[16 rows] @ Ws^T (3-term), D -> LDS ----
    {
        bf16x8 aH[8], aL[8];
#pragma unroll
        for (int kg = 0; kg < 8; ++kg) {
            const size_t o = (qrow + lq) * H_ + kg * 32 + lk * 8;
            aH[kg] = *(const bf16x8*)(q2h + o);
            aL[kg] = *(const bf16x8*)(q2l + o);
        }
        for (int ht = w; ht < 16; ht += 4) {
            f32x4 acc = {};
#pragma unroll
            for (int kg = 0; kg < 8; ++kg) {
                const int fo = ((ht * 8 + kg) * 64 + lk * 16 + lq) * 8;
                const bf16x8 bh = *(const bf16x8*)(wsnh + fo);
                const bf16x8 bl = *(const bf16x8*)(wsnl + fo);
                acc = __builtin_amdgcn_mfma_f32_16x16x32_bf16(aH[kg], bh, acc, 0, 0, 0);
                acc = __builtin_amdgcn_mfma_f32_16x16x32_bf16(aH[kg], bl, acc, 0, 0, 0);
                acc = __builtin_amdgcn_mfma_f32_16x16x32_bf16(aL[kg], bh, acc, 0, 0, 0);
            }
            // D: row t = lk*4+r, col g = ht*16+lq
#pragma unroll
            for (int r = 0; r < 4; ++r) {
                unsigned short h2, l2;
                split1(acc[r], h2, l2);
                const int t = lk * 4 + r;
                unsigned off = (unsigned)(t * 512 + (ht * 16 + lq) * 2);
                off ^= (unsigned)((t & 7) << 4);
                *(unsigned short*)((char*)QSH + off) = h2;
                *(unsigned short*)((char*)QSL + off) = l2;
            }
        }
    }
    __syncthreads();

    // ---- QK^T: A-frags from LDS qs, B from kh/kl ----
    bf16x8 aH[8], aL[8];
#pragma unroll
    for (int hc = 0; hc < 8; ++hc) {
        unsigned off = (unsigned)(lq * 512 + hc * 64 + lk * 16);
        off ^= (unsigned)((lq & 7) << 4);
        aH[hc] = *(const bf16x8*)((const char*)QSH + off);
        aL[hc] = *(const bf16x8*)((const char*)QSL + off);
    }
    for (int st = w; st < 9; st += 4) {
        f32x4 acc = {};
        const int s = s_lo + st * 16 + lq;
        const size_t ro = kb + (size_t)s * H_ + lk * 8;
#pragma unroll
        for (int hc = 0; hc < 8; ++hc) {
            const bf16x8 bh = *(const bf16x8*)(kh + ro + hc * 32);
            const bf16x8 bl = *(const bf16x8*)(kl + ro + hc * 32);
            acc = __builtin_amdgcn_mfma_f32_16x16x32_bf16(aH[hc], bh, acc, 0, 0, 0);
            acc = __builtin_amdgcn_mfma_f32_16x16x32_bf16(aH[hc], bl, acc, 0, 0, 0);
            acc = __builtin_amdgcn_mfma_f32_16x16x32_bf16(aL[hc], bh, acc, 0, 0, 0);
        }
#pragma unroll
        for (int r = 0; r < 4; ++r)
            S[lk * 4 + r][st * 16 + lq] = acc[r];
    }
    __syncthreads();

    // ---- softmax (band-masked, P pre-scaled by 1/denom) ----
    {
        const int q = tid >> 4, li = tid & 15;
        const int t = t0 + q;
        const int jlo = max(0, t - ALEN_) - s_lo;
        const int jhi = t - s_lo;
        float m = -INFINITY;
#pragma unroll
        for (int j = 0; j < 10; ++j) {
            const int s = li + j * 16;
            if (s >= jlo && s <= jhi) m = fmaxf(m, S[q][s]);
        }
#pragma unroll
        for (int off = 8; off; off >>= 1) m = fmaxf(m, __shfl_xor(m, off));
        float sum = 0.f;
#pragma unroll
        for (int j = 0; j < 10; ++j) {
            const int s = li + j * 16;
            const float e = (s >= jlo && s <= jhi) ? expf(S[q][s] - m) : 0.f;
            S[q][s] = e;
            sum += e;
        }
#pragma unroll
        for (int off = 8; off; off >>= 1) sum += __shfl_xor(sum, off);
        const float inv = 1.f / (sum + 1e-30f);
#pragma unroll
        for (int j = 0; j < 10; ++j) {
            const int s = li + j * 16;
            unsigned short hh2, ll2;
            split1(S[q][s] * inv, hh2, ll2);
            PH[q][s] = hh2;
            PL[q][s] = ll2;
        }
    }
    __syncthreads();

    // ---- PV (frag-ordered ktn) ----
    const int gbase = s_lo >> 4;
    for (int ht = w; ht < 16; ht += 4) {
        f32x4 acc = {};
        const unsigned short* ktb = ktn + ((size_t)(b * 16 + ht) * 126) * 256;
#pragma unroll
        for (int sc = 0; sc < 5; ++sc) {
            const bf16x8 ph = *(const bf16x8*)((const char*)&PH[lq][0] + sc * 64 + lk * 16);
            const bf16x8 pl = *(const bf16x8*)((const char*)&PL[lq][0] + sc * 64 + lk * 16);
            const bf16x8 bt = *(const bf16x8*)(
                ktb + (size_t)(gbase + 2 * sc + (lk >> 1)) * 256 + (lk & 1) * 128 + lq * 8);
            acc = __builtin_amdgcn_mfma_f32_16x16x32_bf16(ph, bt, acc, 0, 0, 0);
            acc = __builtin_amdgcn_mfma_f32_16x16x32_bf16(pl, bt, acc, 0, 0, 0);
        }
#pragma unroll
        for (int r = 0; r < 4; ++r) {
            unsigned short hh2, ll2;
            split1(acc[r], hh2, ll2);
            const size_t o = (qrow + lk * 4 + r) * H_ + ht * 16 + lq;
            Ch[o] = hh2;
            Cl[o] = ll2;
        }
    }
}

// ---------------------------------------------------------------------------
// Fused enh+out GEMM (replaces gemm2 + gemm3):
//   stage 1 (R7-proven main loop): enh_tile[64x256] = tanh([c,q] @ We^T + be)
//            -> split -> LDS EH/EL (XOR-swizzled; aliases dead staging bufs)
//   stage 2: out[64x257] = sigmoid(enh_tile @ Wm^T + bm), A-frags from LDS,
//            B-frags from frag-ordered wmn (global, L2-resident), f32 store.
// LDS pointers computed arithmetically (no addrspace-cast pointer arrays).
__global__ __launch_bounds__(256) void gemm_enh_out(
    const unsigned short* __restrict__ Ah1, const unsigned short* __restrict__ Al1,
    const unsigned short* __restrict__ Ah2, const unsigned short* __restrict__ Al2,
    const unsigned short* __restrict__ Wh, const unsigned short* __restrict__ Wl,
    const float* __restrict__ b_enh,
    const unsigned short* __restrict__ wmnh, const unsigned short* __restrict__ wmnl,
    const float* __restrict__ b_mask, float* __restrict__ out)
{
    __shared__ char LDSB[80 * 1024];
    // layout: AS buf0 @0, AS buf1 @8K, WS buf0 @16K, WS buf1 @48K
    // after main loop: EH @0 (32K), EL @32K (32K)

    const int tid = threadIdx.x;
    const int m0 = blockIdx.x * 64;
    const int w = tid >> 6, l = tid & 63;
    const int lm = l & 31, hh = l >> 5;
    constexpr int KB = 512, NT = 16;

    f32x16 acc00 = {}, acc01 = {}, acc10 = {}, acc11 = {};

    auto STAGEA = [&](int kt, int buf) {
        const int k0g = kt * 32;
        const unsigned short* Hs = Ah1;
        const unsigned short* Ls = Al1;
        int k0 = k0g;
        if (k0g >= 256) { Hs = Ah2; Ls = Al2; k0 = k0g - 256; }
        char* base = LDSB + buf * 8192;
#pragma unroll
        for (int p = 0; p < 2; ++p) {
            const unsigned D = p * 4096u + tid * 16u;
            const unsigned row = D >> 7;
            const unsigned u = (D & 127u) ^ ((row & 7u) << 4);
            const unsigned kelem = (u & 63u) >> 1;
            const unsigned short* src =
                ((u >> 6) ? Ls : Hs) + (size_t)(m0 + row) * 256 + k0 + kelem;
            gld16(src, base + (p * 4 + w) * 1024);
        }
    };
    auto STAGEW = [&](int kt, int buf) {
        const int k0g = kt * 32;
        char* base = LDSB + 16 * 1024 + buf * 32768;
#pragma unroll
        for (int p = 0; p < 8; ++p) {
            const unsigned D = p * 4096u + tid * 16u;
            const unsigned row = D >> 7;
            const unsigned u = (D & 127u) ^ ((row & 7u) << 4);
            const unsigned kelem = (u & 63u) >> 1;
            const unsigned short* src =
                ((u >> 6) ? Wl : Wh) + (size_t)row * KB + k0g + kelem;
            gld16(src, base + (p * 4 + w) * 1024);
        }
    };

    STAGEA(0, 0);
    STAGEW(0, 0);
    __syncthreads();

    int buf = 0;
    for (int kt = 0; kt < NT; ++kt) {
        const bool last = (kt == NT - 1);
        if (!last) { STAGEA(kt + 1, buf ^ 1); STAGEW(kt + 1, buf ^ 1); }

        const char* As = LDSB + buf * 8192;
        const char* Wsb = LDSB + 16 * 1024 + buf * 32768;
        const unsigned r_a = (unsigned)lm;
        const unsigned swa = (r_a & 7u) << 4;
        const unsigned r_b = (unsigned)(w * 64 + lm);
        const unsigned swb = (r_b & 7u) << 4;
#pragma unroll
        for (int kc = 0; kc < 2; ++kc) {
            const unsigned u = (unsigned)(kc * 32 + hh * 16);
            const bf16x8 ah0 = *(const bf16x8*)(As + r_a * 128 + (u ^ swa));
            const bf16x8 al0 = *(const bf16x8*)(As + r_a * 128 + ((u + 64) ^ swa));
            const bf16x8 ah1 = *(const bf16x8*)(As + (r_a + 32) * 128 + (u ^ swa));
            const bf16x8 al1 = *(const bf16x8*)(As + (r_a + 32) * 128 + ((u + 64) ^ swa));
            const bf16x8 bh0 = *(const bf16x8*)(Wsb + r_b * 128 + (u ^ swb));
            const bf16x8 bl0 = *(const bf16x8*)(Wsb + r_b * 128 + ((u + 64) ^ swb));
            const bf16x8 bh1 = *(const bf16x8*)(Wsb + (r_b + 32) * 128 + (u ^ swb));
            const bf16x8 bl1 = *(const bf16x8*)(Wsb + (r_b + 32) * 128 + ((u + 64) ^ swb));
            acc00 = __builtin_amdgcn_mfma_f32_32x32x16_bf16(ah0, bh0, acc00, 0, 0, 0);
            acc00 = __builtin_amdgcn_mfma_f32_32x32x16_bf16(ah0, bl0, acc00, 0, 0, 0);
            acc00 = __builtin_amdgcn_mfma_f32_32x32x16_bf16(al0, bh0, acc00, 0, 0, 0);
            acc01 = __builtin_amdgcn_mfma_f32_32x32x16_bf16(ah0, bh1, acc01, 0, 0, 0);
            acc01 = __builtin_amdgcn_mfma_f32_32x32x16_bf16(ah0, bl1, acc01, 0, 0, 0);
            acc01 = __builtin_amdgcn_mfma_f32_32x32x16_bf16(al0, bh1, acc01, 0, 0, 0);
            acc10 = __builtin_amdgcn_mfma_f32_32x32x16_bf16(ah1, bh0, acc10, 0, 0, 0);
            acc10 = __builtin_amdgcn_mfma_f32_32x32x16_bf16(ah1, bl0, acc10, 0, 0, 0);
            acc10 = __builtin_amdgcn_mfma_f32_32x32x16_bf16(al1, bh0, acc10, 0, 0, 0);
            acc11 = __builtin_amdgcn_mfma_f32_32x32x16_bf16(ah1, bh1, acc11, 0, 0, 0);
            acc11 = __builtin_amdgcn_mfma_f32_32x32x16_bf16(ah1, bl1, acc11, 0, 0, 0);
            acc11 = __builtin_amdgcn_mfma_f32_32x32x16_bf16(al1, bh1, acc11, 0, 0, 0);
        }
        __syncthreads();
        buf ^= 1;
    }

    // enh tile -> LDS (split, swizzled). D: col=lane&31, row=(e&3)+8*(e>>2)+4*hh
    {
        char* EH = LDSB;
        char* EL = LDSB + 32 * 1024;
#pragma unroll
        for (int rt = 0; rt < 2; ++rt) {
#pragma unroll
            for (int ct = 0; ct < 2; ++ct) {
                const f32x16 r = rt ? (ct ? acc11 : acc10) : (ct ? acc01 : acc00);
                const int col = w * 64 + ct * 32 + lm;   // 0..255
                const float bv = b_enh[col];
#pragma unroll
                for (int e = 0; e < 16; ++e) {
                    const int row = rt * 32 + (e & 3) + 8 * (e >> 2) + 4 * hh;
                    unsigned short h2, l2;
                    split1(tanhf(r[e] + bv), h2, l2);
                    unsigned off = (unsigned)(row * 512 + col * 2);
                    off ^= (unsigned)((row & 7) << 4);
                    *(unsigned short*)(EH + off) = h2;
                    *(unsigned short*)(EL + off) = l2;
                }
            }
        }
    }
    __syncthreads();

    // out = sigmoid(enh @ Wm^T + bm); wave w does col tiles nt = w, w+4, w+8
    for (int nt = w; nt < 10; nt += 4) {
        const char* EH = LDSB;
        const char* EL = LDSB + 32 * 1024;
        f32x16 o0 = {}, o1 = {};
#pragma unroll
        for (int f = 0; f < 16; ++f) {
            const unsigned kb2 = (unsigned)(f * 32 + hh * 16);
            const unsigned row0 = (unsigned)lm;
            const unsigned sw = (row0 & 7u) << 4;    // (row0+32)&7 == row0&7
            unsigned offA0 = row0 * 512 + kb2;
            unsigned offA1 = (row0 + 32) * 512 + kb2;
            const bf16x8 ah0 = *(const bf16x8*)(EH + (offA0 ^ sw));
            const bf16x8 al0 = *(const bf16x8*)(EL + (offA0 ^ sw));
            const bf16x8 ah1 = *(const bf16x8*)(EH + (offA1 ^ sw));
            const bf16x8 al1 = *(const bf16x8*)(EL + (offA1 ^ sw));
            const size_t bo = ((size_t)((nt * 16 + f) * 2 + hh) * 32 + lm) * 8;
            const bf16x8 bh = *(const bf16x8*)(wmnh + bo);
            const bf16x8 bl = *(const bf16x8*)(wmnl + bo);
            o0 = __builtin_amdgcn_mfma_f32_32x32x16_bf16(ah0, bh, o0, 0, 0, 0);
            o0 = __builtin_amdgcn_mfma_f32_32x32x16_bf16(ah0, bl, o0, 0, 0, 0);
            o0 = __builtin_amdgcn_mfma_f32_32x32x16_bf16(al0, bh, o0, 0, 0, 0);
            o1 = __builtin_amdgcn_mfma_f32_32x32x16_bf16(ah1, bh, o1, 0, 0, 0);
            o1 = __builtin_amdgcn_mfma_f32_32x32x16_bf16(ah1, bl, o1, 0, 0, 0);
            o1 = __builtin_amdgcn_mfma_f32_32x32x16_bf16(al1, bh, o1, 0, 0, 0);
        }
        const int gcol = nt * 32 + lm;
        if (gcol < FOUT_) {
            const float bv = b_mask[gcol];
#pragma unroll
            for (int e = 0; e < 16; ++e) {
                const int rowl = (e & 3) + 8 * (e >> 2) + 4 * hh;
                float x0 = o0[e] + bv, x1 = o1[e] + bv;
                out[(size_t)(m0 + rowl) * FOUT_ + gcol] = 1.f / (1.f + expf(-x0));
                out[(size_t)(m0 + 32 + rowl) * FOUT_ + gcol] = 1.f / (1.f + expf(-x1));
            }
        }
    }
}

// ---------------------------------------------------------------------------
extern "C" void kernel_launch(void* const* d_in, const int* in_sizes, int n_in,
                              void* d_out, int out_size, void* d_ws, size_t ws_size,
                              hipStream_t stream)
{
    const float* k       = (const float*)d_in[0];
    const float* q       = (const float*)d_in[1];
    const float* W_score = (const float*)d_in[2];
    const float* W_enh   = (const float*)d_in[3];
    const float* b_enh   = (const float*)d_in[4];
    const float* W_mask  = (const float*)d_in[5];
    const float* b_mask  = (const float*)d_in[6];
    float* out = (float*)d_out;

    const size_t MH = (size_t)B_ * T_ * H_;          // 4.096M elems
    unsigned short* q2h = (unsigned short*)d_ws;
    unsigned short* q2l = q2h + MH;
    unsigned short* ch  = q2l + MH;
    unsigned short* cl  = ch + MH;
    unsigned short* kh  = cl + MH;
    unsigned short* kl  = kh + MH;
    unsigned short* ktn = kl + MH;                   // 8*16*126*256
    unsigned short* wsnh = ktn + (size_t)B_ * 16 * 126 * 256;
    unsigned short* wsnl = wsnh + 65536;
    unsigned short* weh  = wsnl + 65536;
    unsigned short* wel  = weh + 131072;
    unsigned short* wmnh = wel + 131072;             // 320x256 frag-ordered
    unsigned short* wmnl = wmnh + 81920;

    dim3 blk(256);

    prep<<<dim3(4288), blk, 0, stream>>>(
        k, q, W_score, W_enh, W_mask,
        q2h, q2l, kh, kl, ktn, wsnh, wsnl, weh, wel, wmnh, wmnl);

    band_attn_mfma<<<dim3(1000), blk, 0, stream>>>(
        q2h, q2l, wsnh, wsnl, kh, kl, ktn, ch, cl);

    gemm_enh_out<<<dim3(250), blk, 0, stream>>>(
        ch, cl, q2h, q2l, weh, wel, b_enh, wmnh, wmnl, b_mask, out);
}